// Round 1
// baseline (280.323 us; speedup 1.0000x reference)
//
#include <hip/hip_runtime.h>
#include <hip/hip_bf16.h>

typedef __bf16 bf16x8 __attribute__((ext_vector_type(8)));
typedef float f32x4 __attribute__((ext_vector_type(4)));

#define MFMA16(a,b,c) __builtin_amdgcn_mfma_f32_16x16x32_bf16(a,b,c,0,0,0)
#define GLL16(src, dst) __builtin_amdgcn_global_load_lds( \
    (const __attribute__((address_space(1))) unsigned int*)(src), \
    (__attribute__((address_space(3))) unsigned int*)(dst), 16, 0, 0)

__device__ inline unsigned int pack_bf16(float a, float b) {
    unsigned short ua = __builtin_bit_cast(unsigned short, (__bf16)a);
    unsigned short ub = __builtin_bit_cast(unsigned short, (__bf16)b);
    return ((unsigned int)ub << 16) | ua;
}
__device__ inline short bf_s(float v) {
    __bf16 b = (__bf16)v;
    return __builtin_bit_cast(short, b);
}

// ---------------------------------------------------------------------------
// Fused fp32->bf16: x -> xb, Wq/Wk/Wv -> Wb rows [0,2048)/[2048,2560)/[2560,3072)
// ---------------------------------------------------------------------------
__global__ void cvt_all(const float* __restrict__ x,  const float* __restrict__ wq,
                        const float* __restrict__ wk, const float* __restrict__ wv,
                        __bf16* __restrict__ xb, __bf16* __restrict__ wb) {
    long i = (long)(blockIdx.x * blockDim.x + threadIdx.x) * 8;
    const float* src; __bf16* dst;
    if (i < 8388608)       { src = x  + i;              dst = xb + i; }
    else if (i < 12582912) { src = wq + (i - 8388608);  dst = wb + (i - 8388608); }
    else if (i < 13631488) { src = wk + (i - 12582912); dst = wb + (i - 12582912 + 4194304); }
    else                   { src = wv + (i - 13631488); dst = wb + (i - 13631488 + 5242880); }
    float4 a = *(const float4*)src;
    float4 b = *(const float4*)(src + 4);
    bf16x8 r;
    r[0] = (__bf16)a.x; r[1] = (__bf16)a.y; r[2] = (__bf16)a.z; r[3] = (__bf16)a.w;
    r[4] = (__bf16)b.x; r[5] = (__bf16)b.y; r[6] = (__bf16)b.z; r[7] = (__bf16)b.w;
    *(bf16x8*)dst = r;
}

// ---------------------------------------------------------------------------
// Fused QKV GEMM: C = A·B^T, A=[4096][2048], B=[3072][2048] (Wq|Wk|Wv rows).
// 128x128 tiles, frag-order LDS (lane-linear, conflict-free).
// T4 counted-vmcnt pipeline: TRIPLE-buffered stage (48KB, 3 blocks/CU),
// tile t+2 issued at top of iter t; sync is asm s_waitcnt vmcnt(4) (one tile
// = 4 loads/wave stays in flight across the barrier) + raw s_barrier.
// Wait-THEN-barrier so all waves' tile-(t+1) loads are landed before reads.
// Epilogue routes by tn:
//   tn<16:  Q row-major (scaled by 128^-0.5)
//   16..19: K -> Kf frag-order  [b][g][tb=tok/16][dt=k/32][512]
//   20..23: V -> Vf frag-order  [b][g][ch=tok/64][fb=(d/16)*2+(tok/32)%2][512]
// ---------------------------------------------------------------------------
__global__ __launch_bounds__(256) void gemm_qkv(const __bf16* __restrict__ A,
                                                const __bf16* __restrict__ B,
                                                __bf16* __restrict__ Qb,
                                                __bf16* __restrict__ Kf,
                                                __bf16* __restrict__ Vf,
                                                float qscale) {
    const int K = 2048;
    __shared__ __bf16 As[3 * 4096];   // 24 KB, 3 slots
    __shared__ __bf16 Bs[3 * 4096];   // 24 KB, 3 slots

    int tid = threadIdx.x;
    int wave = tid >> 6, lane = tid & 63;
    int quad = lane >> 4, l16 = lane & 15;

    int tm = blockIdx.x & 31, tn = blockIdx.x >> 5;

    const __bf16* Abase = A + (size_t)tm * 128 * K + (size_t)l16 * K + quad * 8;
    const __bf16* Bbase = B + (size_t)tn * 128 * K + (size_t)l16 * K + quad * 8;

    f32x4 acc[4][4] = {};

    auto stage = [&](int kt, int buf) {
#pragma unroll
        for (int rr = 0; rr < 2; ++rr) {
            int fb = rr * 4 + wave;
            GLL16(Abase + (size_t)fb * 16 * K + kt, As + buf * 4096 + fb * 512 + lane * 8);
            GLL16(Bbase + (size_t)fb * 16 * K + kt, Bs + buf * 4096 + fb * 512 + lane * 8);
        }
    };

    const int nk = K >> 5;   // 64
    stage(0, 0);
    stage(32, 1);
    // 8 loads out; wait to 4 -> tile 0 landed, tile 1 still flying.
    asm volatile("s_waitcnt vmcnt(4)" ::: "memory");
    __builtin_amdgcn_s_barrier();

    int sl = 0, s2 = 2;
    for (int it = 0; it < nk; ++it) {
        // slot s2 = (it+2)%3 == (it-1)%3: last read in iter it-1, behind barrier.
        if (it + 2 < nk) stage((it + 2) << 5, s2);
        const __bf16* Ab = As + sl * 4096;
        const __bf16* Bb = Bs + sl * 4096;
        bf16x8 af[4], bfr[4];
#pragma unroll
        for (int i = 0; i < 4; ++i)
            af[i] = *(const bf16x8*)(Ab + ((wave >> 1) * 4 + i) * 512 + lane * 8);
#pragma unroll
        for (int j = 0; j < 4; ++j)
            bfr[j] = *(const bf16x8*)(Bb + ((wave & 1) * 4 + j) * 512 + lane * 8);
#pragma unroll
        for (int i = 0; i < 4; ++i)
#pragma unroll
            for (int j = 0; j < 4; ++j)
                acc[i][j] = MFMA16(af[i], bfr[j], acc[i][j]);
        if (it + 1 < nk) {
            // need tile it+1 (issued iter it-1) landed; tile it+2 (just issued,
            // 4 loads) may stay in flight -> vmcnt(4). Tail: nothing newer -> 0.
            if (it + 2 < nk) asm volatile("s_waitcnt vmcnt(4)" ::: "memory");
            else             asm volatile("s_waitcnt vmcnt(0)" ::: "memory");
            __builtin_amdgcn_s_barrier();
        }
        sl = (sl == 2) ? 0 : sl + 1;
        s2 = (s2 == 2) ? 0 : s2 + 1;
    }

    int colbase = tn * 128 + (wave & 1) * 64;
#pragma unroll
    for (int i = 0; i < 4; ++i) {
        int row0 = tm * 128 + (wave >> 1) * 64 + i * 16 + quad * 4;
        int b = row0 >> 11, tok0 = row0 & 2047;
#pragma unroll
        for (int j = 0; j < 4; ++j) {
            int col = colbase + j * 16 + l16;
            if (tn < 16) {                       // ---- Q, row-major ----
#pragma unroll
                for (int r = 0; r < 4; ++r)
                    Qb[(size_t)(row0 + r) * 2048 + col] = (__bf16)(acc[i][j][r] * qscale);
            } else if (tn < 20) {                // ---- K frag-order ----
                int d_all = col - 2048;
                int g = d_all >> 7, dd = d_all & 127;
                int dt = dd >> 5, q4 = (dd >> 3) & 3, jj = dd & 7;
                int tb = tok0 >> 4, tl0 = tok0 & 15;
                __bf16* base = Kf + ((((size_t)(b * 4 + g) * 128 + tb) * 4 + dt) * 512)
                               + (q4 * 16 + tl0) * 8 + jj;
#pragma unroll
                for (int r = 0; r < 4; ++r)
                    base[r * 8] = (__bf16)acc[i][j][r];
            } else {                             // ---- V frag-order ----
                int d_all = col - 2560;
                int g = d_all >> 7, dd = d_all & 127;
                int nto = dd >> 4, dl = dd & 15;
                int ch = tok0 >> 6, kk = (tok0 >> 5) & 1;
                int q4v = (tok0 >> 3) & 3, jv0 = tok0 & 7;
                size_t off = ((((size_t)(b * 4 + g) * 32 + ch) * 16) + nto * 2 + kk) * 512
                             + (q4v * 16 + dl) * 8 + jv0;
                short4 pk;
                pk.x = bf_s(acc[i][j][0]); pk.y = bf_s(acc[i][j][1]);
                pk.z = bf_s(acc[i][j][2]); pk.w = bf_s(acc[i][j][3]);
                *(short4*)(Vf + off) = pk;
            }
        }
    }
}

// ---------------------------------------------------------------------------
// Flash attention. Block = (b,g,qb); 4 waves = 4 heads share K/V LDS chunks
// staged via global_load_lds from frag-order Kf/Vf (coalesced 1KB per instr,
// lane-linear ds_read_b128 = conflict-free).
// T4 counted-vmcnt pipeline: K/V DOUBLE-buffered (80KB LDS; grid=512 already
// caps occupancy at 2 blocks/CU, so this is free). Chunk ch+1 staged under
// chunk ch's compute; sync = vmcnt(8) (8 GLL16/wave/stage stay in flight)
// + raw s_barrier, wait-THEN-barrier. P: wave-private frag-order LDS
// round-trip (no barrier).
// qb pairing: slots (63-s, s-32) make per-CU work ~constant.
// ---------------------------------------------------------------------------
__global__ __launch_bounds__(256) void attn_mfma(const __bf16* __restrict__ Q,
                                                 const __bf16* __restrict__ Kf,
                                                 const __bf16* __restrict__ Vf,
                                                 float* __restrict__ O) {
    const int T = 2048, CM = 2048, HD = 128;
    __shared__ __bf16 Ks[2 * 8192];   // 32 KB: buf | fb = t*4+dt
    __shared__ __bf16 Vs[2 * 8192];   // 32 KB: buf | fb = nto*2+kk
    __shared__ __bf16 Pl[8192];       // 4 KB/wave: fb = mt*2+kk

    int tid = threadIdx.x;
    int wave = tid >> 6, lane = tid & 63;
    int quad = lane >> 4, l16 = lane & 15;

    int bg = blockIdx.x & 7;
    int slot = blockIdx.x >> 3;
    int qb = (slot < 32) ? (63 - slot) : (slot - 32);
    int b = bg >> 2, g = bg & 3;
    int h = g * 4 + wave;
    int q0 = qb * 32;

    bf16x8 qf[2][4];
    const __bf16* qbase = Q + (size_t)b * T * CM + (size_t)h * HD;
#pragma unroll
    for (int nt = 0; nt < 2; ++nt)
#pragma unroll
        for (int dt = 0; dt < 4; ++dt)
            qf[nt][dt] = *(const bf16x8*)(qbase + (size_t)(q0 + nt * 16 + l16) * CM
                                          + dt * 32 + quad * 8);

    const __bf16* kcb = Kf + (size_t)(b * 4 + g) * 262144;
    const __bf16* vcb = Vf + (size_t)(b * 4 + g) * 262144;

    float m_r[2] = {-1e30f, -1e30f}, l_r[2] = {0.f, 0.f};
    f32x4 o_acc[2][8] = {};
    __bf16* Pw = Pl + wave * 2048;

    auto stage_kv = [&](int ch, int buf) {
        const __bf16* kg = kcb + ch * 8192 + wave * 2048 + lane * 8;
        const __bf16* vg = vcb + ch * 8192 + wave * 2048 + lane * 8;
        __bf16* kl = Ks + buf * 8192 + wave * 2048 + lane * 8;
        __bf16* vl = Vs + buf * 8192 + wave * 2048 + lane * 8;
#pragma unroll
        for (int i = 0; i < 4; ++i) GLL16(kg + i * 512, kl + i * 512);
#pragma unroll
        for (int i = 0; i < 4; ++i) GLL16(vg + i * 512, vl + i * 512);
    };

    int nch = (qb >> 1) + 1;
    stage_kv(0, 0);
    for (int ch = 0; ch < nch; ++ch) {
        // barrier #1: every wave finished reading buf (ch+1)&1 (= chunk ch-1)
        __builtin_amdgcn_s_barrier();
        if (ch + 1 < nch) {
            stage_kv(ch + 1, (ch + 1) & 1);
            // chunk ch's 8 loads are older than the 8 just issued -> vmcnt(8)
            asm volatile("s_waitcnt vmcnt(8)" ::: "memory");
        } else {
            asm volatile("s_waitcnt vmcnt(0)" ::: "memory");
        }
        // barrier #2: rendezvous -> ALL waves' chunk-ch loads are in LDS
        __builtin_amdgcn_s_barrier();

        const __bf16* Kb = Ks + (ch & 1) * 8192;
        const __bf16* Vb = Vs + (ch & 1) * 8192;

        // ---- S^T = K·Q^T ----
        f32x4 st[2][4] = {};
#pragma unroll
        for (int t = 0; t < 4; ++t)
#pragma unroll
            for (int dt = 0; dt < 4; ++dt) {
                bf16x8 kfv = *(const bf16x8*)(Kb + (t * 4 + dt) * 512 + lane * 8);
                st[0][t] = MFMA16(kfv, qf[0][dt], st[0][t]);
                st[1][t] = MFMA16(kfv, qf[1][dt], st[1][t]);
            }

        bool diag = (ch == nch - 1);
        float alpha[2];
#pragma unroll
        for (int nt = 0; nt < 2; ++nt) {
            if (diag) {
                int qg = q0 + nt * 16 + l16;
#pragma unroll
                for (int t = 0; t < 4; ++t)
#pragma unroll
                    for (int r = 0; r < 4; ++r)
                        if (ch * 64 + t * 16 + quad * 4 + r > qg) st[nt][t][r] = -1e30f;
            }
            float cmax = -1e30f;
#pragma unroll
            for (int t = 0; t < 4; ++t)
                cmax = fmaxf(cmax, fmaxf(fmaxf(st[nt][t][0], st[nt][t][1]),
                                         fmaxf(st[nt][t][2], st[nt][t][3])));
            cmax = fmaxf(cmax, __shfl_xor(cmax, 16));
            cmax = fmaxf(cmax, __shfl_xor(cmax, 32));
            float mnew = fmaxf(m_r[nt], cmax);
            alpha[nt] = __expf(m_r[nt] - mnew);
            m_r[nt] = mnew;
            float ps = 0.f;
#pragma unroll
            for (int t = 0; t < 4; ++t) {
                float p0 = __expf(st[nt][t][0] - mnew);
                float p1 = __expf(st[nt][t][1] - mnew);
                float p2 = __expf(st[nt][t][2] - mnew);
                float p3 = __expf(st[nt][t][3] - mnew);
                ps += (p0 + p1) + (p2 + p3);
                int off = (nt * 2 + (t >> 1)) * 512 + ((t & 1) * 2 + (quad >> 1)) * 128
                          + l16 * 8 + (quad & 1) * 4;
                unsigned long long pk =
                    (unsigned long long)pack_bf16(p0, p1) |
                    ((unsigned long long)pack_bf16(p2, p3) << 32);
                *(unsigned long long*)(Pw + off) = pk;
            }
            ps += __shfl_xor(ps, 16);
            ps += __shfl_xor(ps, 32);
            l_r[nt] = l_r[nt] * alpha[nt] + ps;
        }

        // ---- rescale O ----
#pragma unroll
        for (int mt = 0; mt < 2; ++mt)
#pragma unroll
            for (int r = 0; r < 4; ++r) {
                float alr = __shfl(alpha[mt], quad * 4 + r);
#pragma unroll
                for (int nto = 0; nto < 8; ++nto)
                    o_acc[mt][nto][r] *= alr;
            }

        // ---- O += P·V (P wave-private: no barrier; lgkmcnt orders WAR/RAW) ----
#pragma unroll
        for (int mt = 0; mt < 2; ++mt)
#pragma unroll
            for (int kk = 0; kk < 2; ++kk) {
                bf16x8 pf = *(const bf16x8*)(Pw + (mt * 2 + kk) * 512 + lane * 8);
#pragma unroll
                for (int nto = 0; nto < 8; ++nto) {
                    bf16x8 vf = *(const bf16x8*)(Vb + (nto * 2 + kk) * 512 + lane * 8);
                    o_acc[mt][nto] = MFMA16(pf, vf, o_acc[mt][nto]);
                }
            }
    }

    float* obase = O + (size_t)b * T * CM + (size_t)h * HD;
#pragma unroll
    for (int mt = 0; mt < 2; ++mt) {
        float invl = 1.f / l_r[mt];
#pragma unroll
        for (int r = 0; r < 4; ++r) {
            float ir = __shfl(invl, quad * 4 + r);
            float* orow = obase + (size_t)(q0 + 16 * mt + quad * 4 + r) * CM;
#pragma unroll
            for (int nto = 0; nto < 8; ++nto)
                orow[nto * 16 + l16] = o_acc[mt][nto][r] * ir;
        }
    }
}

extern "C" void kernel_launch(void* const* d_in, const int* in_sizes, int n_in,
                              void* d_out, int out_size, void* d_ws, size_t ws_size,
                              hipStream_t stream) {
    const float* x  = (const float*)d_in[0];
    const float* Wq = (const float*)d_in[1];
    const float* Wk = (const float*)d_in[2];
    const float* Wv = (const float*)d_in[3];
    float* out = (float*)d_out;

    const float qscale = 0.08838834764831845f;  // 128^-0.5

    __bf16* xb = (__bf16*)d_ws;              // 8M elems
    __bf16* Wb = xb + 8388608;               // 6M  [3072][2048] = Wq|Wk|Wv
    __bf16* Qb = Wb + 6291456;               // 8M  [4096][2048]
    __bf16* Kfr = Qb + 8388608;              // 2M  frag-order K
    __bf16* Vfr = Kfr + 2097152;             // 2M  frag-order V

    cvt_all<<<7168, 256, 0, stream>>>(x, Wq, Wk, Wv, xb, Wb);
    gemm_qkv<<<768, 256, 0, stream>>>(xb, Wb, Qb, Kfr, Vfr, qscale);
    attn_mfma<<<512, 256, 0, stream>>>(Qb, Kfr, Vfr, out);
}

// Round 3
// 271.623 us; speedup vs baseline: 1.0320x; 1.0320x over previous
//
#include <hip/hip_runtime.h>
#include <hip/hip_bf16.h>

typedef __bf16 bf16x8 __attribute__((ext_vector_type(8)));
typedef float f32x4 __attribute__((ext_vector_type(4)));

#define MFMA16(a,b,c) __builtin_amdgcn_mfma_f32_16x16x32_bf16(a,b,c,0,0,0)
#define GLL16(src, dst) __builtin_amdgcn_global_load_lds( \
    (const __attribute__((address_space(1))) unsigned int*)(src), \
    (__attribute__((address_space(3))) unsigned int*)(dst), 16, 0, 0)
#define FENCE() asm volatile("" ::: "memory")
#define BARRIER() do { FENCE(); __builtin_amdgcn_s_barrier(); FENCE(); } while (0)

__device__ inline unsigned int pack_bf16(float a, float b) {
    unsigned short ua = __builtin_bit_cast(unsigned short, (__bf16)a);
    unsigned short ub = __builtin_bit_cast(unsigned short, (__bf16)b);
    return ((unsigned int)ub << 16) | ua;
}
__device__ inline short bf_s(float v) {
    __bf16 b = (__bf16)v;
    return __builtin_bit_cast(short, b);
}

// ---------------------------------------------------------------------------
// Fused fp32->bf16: x -> xb, Wq/Wk/Wv -> Wb rows [0,2048)/[2048,2560)/[2560,3072)
// ---------------------------------------------------------------------------
__global__ void cvt_all(const float* __restrict__ x,  const float* __restrict__ wq,
                        const float* __restrict__ wk, const float* __restrict__ wv,
                        __bf16* __restrict__ xb, __bf16* __restrict__ wb) {
    long i = (long)(blockIdx.x * blockDim.x + threadIdx.x) * 8;
    const float* src; __bf16* dst;
    if (i < 8388608)       { src = x  + i;              dst = xb + i; }
    else if (i < 12582912) { src = wq + (i - 8388608);  dst = wb + (i - 8388608); }
    else if (i < 13631488) { src = wk + (i - 12582912); dst = wb + (i - 12582912 + 4194304); }
    else                   { src = wv + (i - 13631488); dst = wb + (i - 13631488 + 5242880); }
    float4 a = *(const float4*)src;
    float4 b = *(const float4*)(src + 4);
    bf16x8 r;
    r[0] = (__bf16)a.x; r[1] = (__bf16)a.y; r[2] = (__bf16)a.z; r[3] = (__bf16)a.w;
    r[4] = (__bf16)b.x; r[5] = (__bf16)b.y; r[6] = (__bf16)b.z; r[7] = (__bf16)b.w;
    *(bf16x8*)dst = r;
}

// ---------------------------------------------------------------------------
// Fused QKV GEMM, 256x256 8-phase template (T3+T4+T5), frag-order LDS.
// C = A·B^T, A=[4096][2048], B=[3072][2048]. Grid 16x12=192, 512 thr (8 waves,
// 2Mx4N), per-wave out 128x64, BK=64, LDS 128KB (2-tile dbuf).
// Per K-tile: 4 phases (mq,nq) = (0,0),(1,0),(0,1),(1,1); each frag LDS-read
// ONCE (held in regs for 2nd use) so quarter-region R of tile t is consumed at
// its read phase; tile t+2's R staged into the SAME buffer one phase later
// (behind barriers -> race-free). vmcnt(8) once per tile: this tile's 8 stage
// loads (t+2) stay in flight, everything older (tile t+1) landed. Never 0 in
// steady loop. setprio(1) around each 16-MFMA cluster.
// Epilogue (tn uniform per block): tn<8 Q row-major; tn 8-9 K frag-order;
// tn 10-11 V frag-order (formulas identical to verified 128² kernel).
// ---------------------------------------------------------------------------
__global__ __launch_bounds__(512, 2) void gemm_qkv(const __bf16* __restrict__ A,
                                                   const __bf16* __restrict__ B,
                                                   __bf16* __restrict__ Qb,
                                                   __bf16* __restrict__ Kf,
                                                   __bf16* __restrict__ Vf,
                                                   float qscale) {
    const int K = 2048;
    const int NT = 32;                 // K-tiles of 64
    __shared__ __bf16 As[2 * 16384];   // 64 KB: [buf][mb*2+ks][512]
    __shared__ __bf16 Bs[2 * 16384];   // 64 KB: [buf][nb*2+ks][512]

    int tid = threadIdx.x;
    int wave = tid >> 6, lane = tid & 63;
    int quad = lane >> 4, l16 = lane & 15;
    int wr = wave >> 2, wc = wave & 3;

    int tm = blockIdx.x & 15, tn = blockIdx.x >> 4;

    const __bf16* Ab = A + (size_t)tm * 256 * K + (size_t)l16 * K + quad * 8;
    const __bf16* Bb = B + (size_t)tn * 256 * K + (size_t)l16 * K + quad * 8;

    // region = 8 {m,n}blocks x 2 ksub = 16 subtiles = 2 GLL16/thread
    auto stageA = [&](int kt, int buf, int mq) {
#pragma unroll
        for (int r = 0; r < 2; ++r) {
            int j = r * 8 + wave;              // 0..15
            int mi = j >> 1, ks = j & 1;
            int mb = (mi & 3) + ((mi >> 2) << 3) + mq * 4;  // {0-3,8-11}+4*mq
            GLL16(Ab + (size_t)mb * 16 * K + kt + ks * 32,
                  As + buf * 16384 + (mb * 2 + ks) * 512 + lane * 8);
        }
    };
    auto stageB = [&](int kt, int buf, int nq) {
#pragma unroll
        for (int r = 0; r < 2; ++r) {
            int j = r * 8 + wave;
            int ni = j >> 1, ks = j & 1;
            int nb = (ni & 1) + ((ni >> 1) << 2) + nq * 2;  // {0,1,4,5,..}+2*nq
            GLL16(Bb + (size_t)nb * 16 * K + kt + ks * 32,
                  Bs + buf * 16384 + (nb * 2 + ks) * 512 + lane * 8);
        }
    };

    f32x4 acc[8][4] = {};

    // prologue: tiles 0 (buf0) and 1 (buf1); wait tile0 landed, tile1 in flight
    stageA(0, 0, 0); stageB(0, 0, 0); stageA(0, 0, 1); stageB(0, 0, 1);
    stageA(64, 1, 0); stageB(64, 1, 0); stageA(64, 1, 1); stageB(64, 1, 1);
    asm volatile("s_waitcnt vmcnt(8)" ::: "memory");
    BARRIER();

    for (int t = 0; t < NT; ++t) {
        const __bf16* Ac = As + (t & 1) * 16384;
        const __bf16* Bc = Bs + (t & 1) * 16384;
        int kt2 = (t + 2) << 6;
        bool st = (t + 2) < NT;
        int bn = t & 1;                 // (t+2)&1 == t&1

        bf16x8 a0[4][2], a1[4][2], b0[2][2], b1[2][2];

        // ---- phase 1: (mq0,nq0) — 12 ds_reads, 16 MFMA ----
#pragma unroll
        for (int m = 0; m < 4; ++m)
#pragma unroll
            for (int ks = 0; ks < 2; ++ks)
                a0[m][ks] = *(const bf16x8*)(Ac + ((wr * 8 + m) * 2 + ks) * 512 + lane * 8);
#pragma unroll
        for (int n = 0; n < 2; ++n)
#pragma unroll
            for (int ks = 0; ks < 2; ++ks)
                b0[n][ks] = *(const bf16x8*)(Bc + ((wc * 4 + n) * 2 + ks) * 512 + lane * 8);
        BARRIER();
        __builtin_amdgcn_s_setprio(1);
#pragma unroll
        for (int m = 0; m < 4; ++m)
#pragma unroll
            for (int n = 0; n < 2; ++n)
#pragma unroll
                for (int ks = 0; ks < 2; ++ks)
                    acc[m][n] = MFMA16(a0[m][ks], b0[n][ks], acc[m][n]);
        __builtin_amdgcn_s_setprio(0);
        BARRIER();

        // ---- phase 2: (mq1,nq0) — 8 ds_reads, stage A0+B0(t+2), 16 MFMA ----
#pragma unroll
        for (int m = 0; m < 4; ++m)
#pragma unroll
            for (int ks = 0; ks < 2; ++ks)
                a1[m][ks] = *(const bf16x8*)(Ac + ((wr * 8 + 4 + m) * 2 + ks) * 512 + lane * 8);
        if (st) { stageA(kt2, bn, 0); stageB(kt2, bn, 0); }
        BARRIER();
        __builtin_amdgcn_s_setprio(1);
#pragma unroll
        for (int m = 0; m < 4; ++m)
#pragma unroll
            for (int n = 0; n < 2; ++n)
#pragma unroll
                for (int ks = 0; ks < 2; ++ks)
                    acc[4 + m][n] = MFMA16(a1[m][ks], b0[n][ks], acc[4 + m][n]);
        __builtin_amdgcn_s_setprio(0);
        BARRIER();

        // ---- phase 3: (mq0,nq1) — 4 ds_reads, stage A1(t+2), 16 MFMA ----
#pragma unroll
        for (int n = 0; n < 2; ++n)
#pragma unroll
            for (int ks = 0; ks < 2; ++ks)
                b1[n][ks] = *(const bf16x8*)(Bc + ((wc * 4 + 2 + n) * 2 + ks) * 512 + lane * 8);
        if (st) stageA(kt2, bn, 1);
        BARRIER();
        __builtin_amdgcn_s_setprio(1);
#pragma unroll
        for (int m = 0; m < 4; ++m)
#pragma unroll
            for (int n = 0; n < 2; ++n)
#pragma unroll
                for (int ks = 0; ks < 2; ++ks)
                    acc[m][2 + n] = MFMA16(a0[m][ks], b1[n][ks], acc[m][2 + n]);
        __builtin_amdgcn_s_setprio(0);
        BARRIER();

        // ---- phase 4: (mq1,nq1) — stage B1(t+2), 16 MFMA, counted vmcnt ----
        if (st) stageB(kt2, bn, 1);
        BARRIER();
        __builtin_amdgcn_s_setprio(1);
#pragma unroll
        for (int m = 0; m < 4; ++m)
#pragma unroll
            for (int n = 0; n < 2; ++n)
#pragma unroll
                for (int ks = 0; ks < 2; ++ks)
                    acc[4 + m][2 + n] = MFMA16(a1[m][ks], b1[n][ks], acc[4 + m][2 + n]);
        __builtin_amdgcn_s_setprio(0);
        if (t < NT - 2)       asm volatile("s_waitcnt vmcnt(8)" ::: "memory");
        else if (t == NT - 2) asm volatile("s_waitcnt vmcnt(0)" ::: "memory");
        BARRIER();
    }

    // ---- epilogue: route by tn (block-uniform) ----
#pragma unroll
    for (int m = 0; m < 8; ++m) {
        int row0 = tm * 256 + wr * 128 + m * 16 + quad * 4;
        int bb = row0 >> 11, tok0 = row0 & 2047;
#pragma unroll
        for (int n = 0; n < 4; ++n) {
            int col = tn * 256 + wc * 64 + n * 16 + l16;
            if (tn < 8) {                        // ---- Q, row-major ----
#pragma unroll
                for (int r = 0; r < 4; ++r)
                    Qb[(size_t)(row0 + r) * 2048 + col] = (__bf16)(acc[m][n][r] * qscale);
            } else if (tn < 10) {                // ---- K frag-order ----
                int d_all = col - 2048;
                int g = d_all >> 7, dd = d_all & 127;
                int dt = dd >> 5, q4 = (dd >> 3) & 3, jj = dd & 7;
                int tb = tok0 >> 4, tl0 = tok0 & 15;
                __bf16* base = Kf + ((((size_t)(bb * 4 + g) * 128 + tb) * 4 + dt) * 512)
                               + (q4 * 16 + tl0) * 8 + jj;
#pragma unroll
                for (int r = 0; r < 4; ++r)
                    base[r * 8] = (__bf16)acc[m][n][r];
            } else {                             // ---- V frag-order ----
                int d_all = col - 2560;
                int g = d_all >> 7, dd = d_all & 127;
                int nto = dd >> 4, dl = dd & 15;
                int ch = tok0 >> 6, kk = (tok0 >> 5) & 1;
                int q4v = (tok0 >> 3) & 3, jv0 = tok0 & 7;
                size_t off = ((((size_t)(bb * 4 + g) * 32 + ch) * 16) + nto * 2 + kk) * 512
                             + (q4v * 16 + dl) * 8 + jv0;
                short4 pk;
                pk.x = bf_s(acc[m][n][0]); pk.y = bf_s(acc[m][n][1]);
                pk.z = bf_s(acc[m][n][2]); pk.w = bf_s(acc[m][n][3]);
                *(short4*)(Vf + off) = pk;
            }
        }
    }
}

// ---------------------------------------------------------------------------
// Flash attention. Block = (b,g,qb); 4 waves = 4 heads share K/V LDS chunks
// staged via global_load_lds from frag-order Kf/Vf. Double-buffered K/V with
// counted vmcnt(8); T5 setprio around both MFMA clusters (m191: +4-7%).
// P: wave-private frag-order LDS round-trip (no barrier).
// ---------------------------------------------------------------------------
__global__ __launch_bounds__(256) void attn_mfma(const __bf16* __restrict__ Q,
                                                 const __bf16* __restrict__ Kf,
                                                 const __bf16* __restrict__ Vf,
                                                 float* __restrict__ O) {
    const int T = 2048, CM = 2048, HD = 128;
    __shared__ __bf16 Ks[2 * 8192];   // 32 KB: buf | fb = t*4+dt
    __shared__ __bf16 Vs[2 * 8192];   // 32 KB: buf | fb = nto*2+kk
    __shared__ __bf16 Pl[8192];       // 4 KB/wave: fb = mt*2+kk

    int tid = threadIdx.x;
    int wave = tid >> 6, lane = tid & 63;
    int quad = lane >> 4, l16 = lane & 15;

    int bg = blockIdx.x & 7;
    int slot = blockIdx.x >> 3;
    int qb = (slot < 32) ? (63 - slot) : (slot - 32);
    int b = bg >> 2, g = bg & 3;
    int h = g * 4 + wave;
    int q0 = qb * 32;

    bf16x8 qf[2][4];
    const __bf16* qbase = Q + (size_t)b * T * CM + (size_t)h * HD;
#pragma unroll
    for (int nt = 0; nt < 2; ++nt)
#pragma unroll
        for (int dt = 0; dt < 4; ++dt)
            qf[nt][dt] = *(const bf16x8*)(qbase + (size_t)(q0 + nt * 16 + l16) * CM
                                          + dt * 32 + quad * 8);

    const __bf16* kcb = Kf + (size_t)(b * 4 + g) * 262144;
    const __bf16* vcb = Vf + (size_t)(b * 4 + g) * 262144;

    float m_r[2] = {-1e30f, -1e30f}, l_r[2] = {0.f, 0.f};
    f32x4 o_acc[2][8] = {};
    __bf16* Pw = Pl + wave * 2048;

    auto stage_kv = [&](int ch, int buf) {
        const __bf16* kg = kcb + ch * 8192 + wave * 2048 + lane * 8;
        const __bf16* vg = vcb + ch * 8192 + wave * 2048 + lane * 8;
        __bf16* kl = Ks + buf * 8192 + wave * 2048 + lane * 8;
        __bf16* vl = Vs + buf * 8192 + wave * 2048 + lane * 8;
#pragma unroll
        for (int i = 0; i < 4; ++i) GLL16(kg + i * 512, kl + i * 512);
#pragma unroll
        for (int i = 0; i < 4; ++i) GLL16(vg + i * 512, vl + i * 512);
    };

    int nch = (qb >> 1) + 1;
    stage_kv(0, 0);
    for (int ch = 0; ch < nch; ++ch) {
        // barrier #1: every wave finished reading buf (ch+1)&1 (= chunk ch-1)
        BARRIER();
        if (ch + 1 < nch) {
            stage_kv(ch + 1, (ch + 1) & 1);
            asm volatile("s_waitcnt vmcnt(8)" ::: "memory");
        } else {
            asm volatile("s_waitcnt vmcnt(0)" ::: "memory");
        }
        // barrier #2: rendezvous -> ALL waves' chunk-ch loads are in LDS
        BARRIER();

        const __bf16* Kb = Ks + (ch & 1) * 8192;
        const __bf16* Vb = Vs + (ch & 1) * 8192;

        // ---- S^T = K·Q^T ----
        f32x4 st[2][4] = {};
        __builtin_amdgcn_s_setprio(1);
#pragma unroll
        for (int t = 0; t < 4; ++t)
#pragma unroll
            for (int dt = 0; dt < 4; ++dt) {
                bf16x8 kfv = *(const bf16x8*)(Kb + (t * 4 + dt) * 512 + lane * 8);
                st[0][t] = MFMA16(kfv, qf[0][dt], st[0][t]);
                st[1][t] = MFMA16(kfv, qf[1][dt], st[1][t]);
            }
        __builtin_amdgcn_s_setprio(0);

        bool diag = (ch == nch - 1);
        float alpha[2];
#pragma unroll
        for (int nt = 0; nt < 2; ++nt) {
            if (diag) {
                int qg = q0 + nt * 16 + l16;
#pragma unroll
                for (int t = 0; t < 4; ++t)
#pragma unroll
                    for (int r = 0; r < 4; ++r)
                        if (ch * 64 + t * 16 + quad * 4 + r > qg) st[nt][t][r] = -1e30f;
            }
            float cmax = -1e30f;
#pragma unroll
            for (int t = 0; t < 4; ++t)
                cmax = fmaxf(cmax, fmaxf(fmaxf(st[nt][t][0], st[nt][t][1]),
                                         fmaxf(st[nt][t][2], st[nt][t][3])));
            cmax = fmaxf(cmax, __shfl_xor(cmax, 16));
            cmax = fmaxf(cmax, __shfl_xor(cmax, 32));
            float mnew = fmaxf(m_r[nt], cmax);
            alpha[nt] = __expf(m_r[nt] - mnew);
            m_r[nt] = mnew;
            float ps = 0.f;
#pragma unroll
            for (int t = 0; t < 4; ++t) {
                float p0 = __expf(st[nt][t][0] - mnew);
                float p1 = __expf(st[nt][t][1] - mnew);
                float p2 = __expf(st[nt][t][2] - mnew);
                float p3 = __expf(st[nt][t][3] - mnew);
                ps += (p0 + p1) + (p2 + p3);
                int off = (nt * 2 + (t >> 1)) * 512 + ((t & 1) * 2 + (quad >> 1)) * 128
                          + l16 * 8 + (quad & 1) * 4;
                unsigned long long pk =
                    (unsigned long long)pack_bf16(p0, p1) |
                    ((unsigned long long)pack_bf16(p2, p3) << 32);
                *(unsigned long long*)(Pw + off) = pk;
            }
            ps += __shfl_xor(ps, 16);
            ps += __shfl_xor(ps, 32);
            l_r[nt] = l_r[nt] * alpha[nt] + ps;
        }

        // ---- rescale O ----
#pragma unroll
        for (int mt = 0; mt < 2; ++mt)
#pragma unroll
            for (int r = 0; r < 4; ++r) {
                float alr = __shfl(alpha[mt], quad * 4 + r);
#pragma unroll
                for (int nto = 0; nto < 8; ++nto)
                    o_acc[mt][nto][r] *= alr;
            }

        // ---- O += P·V (P wave-private: no barrier; lgkmcnt orders WAR/RAW) ----
        __builtin_amdgcn_s_setprio(1);
#pragma unroll
        for (int mt = 0; mt < 2; ++mt)
#pragma unroll
            for (int kk = 0; kk < 2; ++kk) {
                bf16x8 pf = *(const bf16x8*)(Pw + (mt * 2 + kk) * 512 + lane * 8);
#pragma unroll
                for (int nto = 0; nto < 8; ++nto) {
                    bf16x8 vf = *(const bf16x8*)(Vb + (nto * 2 + kk) * 512 + lane * 8);
                    o_acc[mt][nto] = MFMA16(pf, vf, o_acc[mt][nto]);
                }
            }
        __builtin_amdgcn_s_setprio(0);
    }

    float* obase = O + (size_t)b * T * CM + (size_t)h * HD;
#pragma unroll
    for (int mt = 0; mt < 2; ++mt) {
        float invl = 1.f / l_r[mt];
#pragma unroll
        for (int r = 0; r < 4; ++r) {
            float ir = __shfl(invl, quad * 4 + r);
            float* orow = obase + (size_t)(q0 + 16 * mt + quad * 4 + r) * CM;
#pragma unroll
            for (int nto = 0; nto < 8; ++nto)
                orow[nto * 16 + l16] = o_acc[mt][nto][r] * ir;
        }
    }
}

extern "C" void kernel_launch(void* const* d_in, const int* in_sizes, int n_in,
                              void* d_out, int out_size, void* d_ws, size_t ws_size,
                              hipStream_t stream) {
    const float* x  = (const float*)d_in[0];
    const float* Wq = (const float*)d_in[1];
    const float* Wk = (const float*)d_in[2];
    const float* Wv = (const float*)d_in[3];
    float* out = (float*)d_out;

    const float qscale = 0.08838834764831845f;  // 128^-0.5

    __bf16* xb = (__bf16*)d_ws;              // 8M elems
    __bf16* Wb = xb + 8388608;               // 6M  [3072][2048] = Wq|Wk|Wv
    __bf16* Qb = Wb + 6291456;               // 8M  [4096][2048]
    __bf16* Kfr = Qb + 8388608;              // 2M  frag-order K
    __bf16* Vfr = Kfr + 2097152;             // 2M  frag-order V

    cvt_all<<<7168, 256, 0, stream>>>(x, Wq, Wk, Wv, xb, Wb);
    gemm_qkv<<<192, 512, 0, stream>>>(xb, Wb, Qb, Kfr, Vfr, qscale);
    attn_mfma<<<512, 256, 0, stream>>>(Qb, Kfr, Vfr, out);
}

// Round 4
// 271.284 us; speedup vs baseline: 1.0333x; 1.0012x over previous
//
#include <hip/hip_runtime.h>
#include <hip/hip_bf16.h>

typedef __bf16 bf16x8 __attribute__((ext_vector_type(8)));
typedef float f32x4 __attribute__((ext_vector_type(4)));

#define MFMA16(a,b,c) __builtin_amdgcn_mfma_f32_16x16x32_bf16(a,b,c,0,0,0)
#define GLL16(src, dst) __builtin_amdgcn_global_load_lds( \
    (const __attribute__((address_space(1))) unsigned int*)(src), \
    (__attribute__((address_space(3))) unsigned int*)(dst), 16, 0, 0)
// BARE waits/barrier — NO "memory" clobber. A memory-clobbered asm makes
// SIInsertWaitcnts conservatively drain vmcnt(0)+lgkmcnt(0) before it,
// which silently defeats counted-vmcnt pipelining (round-1/3 nulls).
#define WAIT_VM(n)  asm volatile("s_waitcnt vmcnt(" #n ")")
#define WAIT_LGKM0() asm volatile("s_waitcnt lgkmcnt(0)")
#define BAR() __builtin_amdgcn_s_barrier()

__device__ inline unsigned int pack_bf16(float a, float b) {
    unsigned short ua = __builtin_bit_cast(unsigned short, (__bf16)a);
    unsigned short ub = __builtin_bit_cast(unsigned short, (__bf16)b);
    return ((unsigned int)ub << 16) | ua;
}
__device__ inline short bf_s(float v) {
    __bf16 b = (__bf16)v;
    return __builtin_bit_cast(short, b);
}

// ---------------------------------------------------------------------------
// Fused fp32->bf16: x -> xb, Wq/Wk/Wv -> Wb rows [0,2048)/[2048,2560)/[2560,3072)
// ---------------------------------------------------------------------------
__global__ void cvt_all(const float* __restrict__ x,  const float* __restrict__ wq,
                        const float* __restrict__ wk, const float* __restrict__ wv,
                        __bf16* __restrict__ xb, __bf16* __restrict__ wb) {
    long i = (long)(blockIdx.x * blockDim.x + threadIdx.x) * 8;
    const float* src; __bf16* dst;
    if (i < 8388608)       { src = x  + i;              dst = xb + i; }
    else if (i < 12582912) { src = wq + (i - 8388608);  dst = wb + (i - 8388608); }
    else if (i < 13631488) { src = wk + (i - 12582912); dst = wb + (i - 12582912 + 4194304); }
    else                   { src = wv + (i - 13631488); dst = wb + (i - 13631488 + 5242880); }
    float4 a = *(const float4*)src;
    float4 b = *(const float4*)(src + 4);
    bf16x8 r;
    r[0] = (__bf16)a.x; r[1] = (__bf16)a.y; r[2] = (__bf16)a.z; r[3] = (__bf16)a.w;
    r[4] = (__bf16)b.x; r[5] = (__bf16)b.y; r[6] = (__bf16)b.z; r[7] = (__bf16)b.w;
    *(bf16x8*)dst = r;
}

// ---------------------------------------------------------------------------
// Fused QKV GEMM, 256x256 8-phase template (T3+T4+T5), frag-order LDS.
// C = A·B^T, A=[4096][2048], B=[3072][2048]. Grid 16x12=192, 512 thr (8 waves,
// 2Mx4N), per-wave out 128x64, BK=64, LDS 128KB (2-tile dbuf).
// Per K-tile: 4 phases (mq,nq)=(0,0),(1,0),(0,1),(1,1); each frag LDS-read
// ONCE (held in regs for 2nd use); tile t+2's region staged into the same
// buffer one phase after tile t's copy was consumed (behind barriers).
// vmcnt(8) once per tile: tile t+2's 8 loads stay in flight, tile t+1's
// (issued a full tile = 4 phases ago) are required landed. Bare asm waits —
// see macro note. MFMA clusters ks-outer: 8 independent MFMAs between
// dependent pairs. setprio(1) around each cluster.
// ---------------------------------------------------------------------------
__global__ __launch_bounds__(512, 2) void gemm_qkv(const __bf16* __restrict__ A,
                                                   const __bf16* __restrict__ B,
                                                   __bf16* __restrict__ Qb,
                                                   __bf16* __restrict__ Kf,
                                                   __bf16* __restrict__ Vf,
                                                   float qscale) {
    const int K = 2048;
    const int NT = 32;                 // K-tiles of 64
    __shared__ __bf16 As[2 * 16384];   // 64 KB: [buf][mb*2+ks][512]
    __shared__ __bf16 Bs[2 * 16384];   // 64 KB: [buf][nb*2+ks][512]

    int tid = threadIdx.x;
    int wave = tid >> 6, lane = tid & 63;
    int quad = lane >> 4, l16 = lane & 15;
    int wr = wave >> 2, wc = wave & 3;

    int tm = blockIdx.x & 15, tn = blockIdx.x >> 4;

    const __bf16* Ab = A + (size_t)tm * 256 * K + (size_t)l16 * K + quad * 8;
    const __bf16* Bb = B + (size_t)tn * 256 * K + (size_t)l16 * K + quad * 8;

    // region = 8 {m,n}blocks x 2 ksub = 16 subtiles = 2 GLL16/thread
    auto stageA = [&](int kt, int buf, int mq) {
#pragma unroll
        for (int r = 0; r < 2; ++r) {
            int j = r * 8 + wave;              // 0..15
            int mi = j >> 1, ks = j & 1;
            int mb = (mi & 3) + ((mi >> 2) << 3) + mq * 4;  // {0-3,8-11}+4*mq
            GLL16(Ab + (size_t)mb * 16 * K + kt + ks * 32,
                  As + buf * 16384 + (mb * 2 + ks) * 512 + lane * 8);
        }
    };
    auto stageB = [&](int kt, int buf, int nq) {
#pragma unroll
        for (int r = 0; r < 2; ++r) {
            int j = r * 8 + wave;
            int ni = j >> 1, ks = j & 1;
            int nb = (ni & 1) + ((ni >> 1) << 2) + nq * 2;  // {0,1,4,5,..}+2*nq
            GLL16(Bb + (size_t)nb * 16 * K + kt + ks * 32,
                  Bs + buf * 16384 + (nb * 2 + ks) * 512 + lane * 8);
        }
    };

    f32x4 acc[8][4] = {};

    // prologue: tiles 0 (buf0) and 1 (buf1); wait tile0 landed, tile1 in flight
    stageA(0, 0, 0); stageB(0, 0, 0); stageA(0, 0, 1); stageB(0, 0, 1);
    stageA(64, 1, 0); stageB(64, 1, 0); stageA(64, 1, 1); stageB(64, 1, 1);
    WAIT_VM(8);
    BAR();

    for (int t = 0; t < NT; ++t) {
        const __bf16* Ac = As + (t & 1) * 16384;
        const __bf16* Bc = Bs + (t & 1) * 16384;
        int kt2 = (t + 2) << 6;
        bool st = (t + 2) < NT;
        int bn = t & 1;                 // (t+2)&1 == t&1

        bf16x8 a0[4][2], a1[4][2], b0[2][2], b1[2][2];

        // ---- phase 1: (mq0,nq0) — 12 ds_reads, 16 MFMA ----
#pragma unroll
        for (int m = 0; m < 4; ++m)
#pragma unroll
            for (int ks = 0; ks < 2; ++ks)
                a0[m][ks] = *(const bf16x8*)(Ac + ((wr * 8 + m) * 2 + ks) * 512 + lane * 8);
#pragma unroll
        for (int n = 0; n < 2; ++n)
#pragma unroll
            for (int ks = 0; ks < 2; ++ks)
                b0[n][ks] = *(const bf16x8*)(Bc + ((wc * 4 + n) * 2 + ks) * 512 + lane * 8);
        asm volatile("s_waitcnt lgkmcnt(8)");   // template: bound LDS queue pre-barrier
        BAR();
        WAIT_LGKM0();
        __builtin_amdgcn_s_setprio(1);
#pragma unroll
        for (int ks = 0; ks < 2; ++ks)
#pragma unroll
            for (int m = 0; m < 4; ++m)
#pragma unroll
                for (int n = 0; n < 2; ++n)
                    acc[m][n] = MFMA16(a0[m][ks], b0[n][ks], acc[m][n]);
        __builtin_amdgcn_s_setprio(0);
        BAR();

        // ---- phase 2: (mq1,nq0) — 8 ds_reads, stage A0+B0(t+2), 16 MFMA ----
#pragma unroll
        for (int m = 0; m < 4; ++m)
#pragma unroll
            for (int ks = 0; ks < 2; ++ks)
                a1[m][ks] = *(const bf16x8*)(Ac + ((wr * 8 + 4 + m) * 2 + ks) * 512 + lane * 8);
        if (st) { stageA(kt2, bn, 0); stageB(kt2, bn, 0); }
        BAR();
        WAIT_LGKM0();
        __builtin_amdgcn_s_setprio(1);
#pragma unroll
        for (int ks = 0; ks < 2; ++ks)
#pragma unroll
            for (int m = 0; m < 4; ++m)
#pragma unroll
                for (int n = 0; n < 2; ++n)
                    acc[4 + m][n] = MFMA16(a1[m][ks], b0[n][ks], acc[4 + m][n]);
        __builtin_amdgcn_s_setprio(0);
        BAR();

        // ---- phase 3: (mq0,nq1) — 4 ds_reads, stage A1(t+2), 16 MFMA ----
#pragma unroll
        for (int n = 0; n < 2; ++n)
#pragma unroll
            for (int ks = 0; ks < 2; ++ks)
                b1[n][ks] = *(const bf16x8*)(Bc + ((wc * 4 + 2 + n) * 2 + ks) * 512 + lane * 8);
        if (st) stageA(kt2, bn, 1);
        BAR();
        WAIT_LGKM0();
        __builtin_amdgcn_s_setprio(1);
#pragma unroll
        for (int ks = 0; ks < 2; ++ks)
#pragma unroll
            for (int m = 0; m < 4; ++m)
#pragma unroll
                for (int n = 0; n < 2; ++n)
                    acc[m][2 + n] = MFMA16(a0[m][ks], b1[n][ks], acc[m][2 + n]);
        __builtin_amdgcn_s_setprio(0);
        BAR();

        // ---- phase 4: (mq1,nq1) — stage B1(t+2), 16 MFMA, counted vmcnt ----
        if (st) stageB(kt2, bn, 1);
        BAR();
        __builtin_amdgcn_s_setprio(1);
#pragma unroll
        for (int ks = 0; ks < 2; ++ks)
#pragma unroll
            for (int m = 0; m < 4; ++m)
#pragma unroll
                for (int n = 0; n < 2; ++n)
                    acc[4 + m][2 + n] = MFMA16(a1[m][ks], b1[n][ks], acc[4 + m][2 + n]);
        __builtin_amdgcn_s_setprio(0);
        // need tile t+1 (staged during tile t-1, 4-7 phases old) landed;
        // tile t+2's 8 loads (staged this tile) stay in flight.
        if (t < NT - 2)       WAIT_VM(8);
        else if (t == NT - 2) WAIT_VM(0);
        BAR();
    }

    // ---- epilogue: route by tn (block-uniform) ----
#pragma unroll
    for (int m = 0; m < 8; ++m) {
        int row0 = tm * 256 + wr * 128 + m * 16 + quad * 4;
        int bb = row0 >> 11, tok0 = row0 & 2047;
#pragma unroll
        for (int n = 0; n < 4; ++n) {
            int col = tn * 256 + wc * 64 + n * 16 + l16;
            if (tn < 8) {                        // ---- Q, row-major ----
#pragma unroll
                for (int r = 0; r < 4; ++r)
                    Qb[(size_t)(row0 + r) * 2048 + col] = (__bf16)(acc[m][n][r] * qscale);
            } else if (tn < 10) {                // ---- K frag-order ----
                int d_all = col - 2048;
                int g = d_all >> 7, dd = d_all & 127;
                int dt = dd >> 5, q4 = (dd >> 3) & 3, jj = dd & 7;
                int tb = tok0 >> 4, tl0 = tok0 & 15;
                __bf16* base = Kf + ((((size_t)(bb * 4 + g) * 128 + tb) * 4 + dt) * 512)
                               + (q4 * 16 + tl0) * 8 + jj;
#pragma unroll
                for (int r = 0; r < 4; ++r)
                    base[r * 8] = (__bf16)acc[m][n][r];
            } else {                             // ---- V frag-order ----
                int d_all = col - 2560;
                int g = d_all >> 7, dd = d_all & 127;
                int nto = dd >> 4, dl = dd & 15;
                int ch = tok0 >> 6, kk = (tok0 >> 5) & 1;
                int q4v = (tok0 >> 3) & 3, jv0 = tok0 & 7;
                size_t off = ((((size_t)(bb * 4 + g) * 32 + ch) * 16) + nto * 2 + kk) * 512
                             + (q4v * 16 + dl) * 8 + jv0;
                short4 pk;
                pk.x = bf_s(acc[m][n][0]); pk.y = bf_s(acc[m][n][1]);
                pk.z = bf_s(acc[m][n][2]); pk.w = bf_s(acc[m][n][3]);
                *(short4*)(Vf + off) = pk;
            }
        }
    }
}

// ---------------------------------------------------------------------------
// Flash attention. Block = (b,g,qb); 4 waves = 4 heads share K/V LDS chunks
// staged via global_load_lds from frag-order Kf/Vf. Double-buffered K/V with
// counted vmcnt(8) (bare asm — see macro note); T5 setprio around both MFMA
// clusters. P: wave-private frag-order LDS round-trip (no barrier).
// ---------------------------------------------------------------------------
__global__ __launch_bounds__(256) void attn_mfma(const __bf16* __restrict__ Q,
                                                 const __bf16* __restrict__ Kf,
                                                 const __bf16* __restrict__ Vf,
                                                 float* __restrict__ O) {
    const int T = 2048, CM = 2048, HD = 128;
    __shared__ __bf16 Ks[2 * 8192];   // 32 KB: buf | fb = t*4+dt
    __shared__ __bf16 Vs[2 * 8192];   // 32 KB: buf | fb = nto*2+kk
    __shared__ __bf16 Pl[8192];       // 4 KB/wave: fb = mt*2+kk

    int tid = threadIdx.x;
    int wave = tid >> 6, lane = tid & 63;
    int quad = lane >> 4, l16 = lane & 15;

    int bg = blockIdx.x & 7;
    int slot = blockIdx.x >> 3;
    int qb = (slot < 32) ? (63 - slot) : (slot - 32);
    int b = bg >> 2, g = bg & 3;
    int h = g * 4 + wave;
    int q0 = qb * 32;

    bf16x8 qf[2][4];
    const __bf16* qbase = Q + (size_t)b * T * CM + (size_t)h * HD;
#pragma unroll
    for (int nt = 0; nt < 2; ++nt)
#pragma unroll
        for (int dt = 0; dt < 4; ++dt)
            qf[nt][dt] = *(const bf16x8*)(qbase + (size_t)(q0 + nt * 16 + l16) * CM
                                          + dt * 32 + quad * 8);

    const __bf16* kcb = Kf + (size_t)(b * 4 + g) * 262144;
    const __bf16* vcb = Vf + (size_t)(b * 4 + g) * 262144;

    float m_r[2] = {-1e30f, -1e30f}, l_r[2] = {0.f, 0.f};
    f32x4 o_acc[2][8] = {};
    __bf16* Pw = Pl + wave * 2048;

    auto stage_kv = [&](int ch, int buf) {
        const __bf16* kg = kcb + ch * 8192 + wave * 2048 + lane * 8;
        const __bf16* vg = vcb + ch * 8192 + wave * 2048 + lane * 8;
        __bf16* kl = Ks + buf * 8192 + wave * 2048 + lane * 8;
        __bf16* vl = Vs + buf * 8192 + wave * 2048 + lane * 8;
#pragma unroll
        for (int i = 0; i < 4; ++i) GLL16(kg + i * 512, kl + i * 512);
#pragma unroll
        for (int i = 0; i < 4; ++i) GLL16(vg + i * 512, vl + i * 512);
    };

    int nch = (qb >> 1) + 1;
    stage_kv(0, 0);
    for (int ch = 0; ch < nch; ++ch) {
        // barrier #1: every wave finished reading buf (ch+1)&1 (= chunk ch-1)
        BAR();
        if (ch + 1 < nch) {
            stage_kv(ch + 1, (ch + 1) & 1);
            WAIT_VM(8);   // chunk ch's 8 loads older than the 8 just issued
        } else {
            WAIT_VM(0);
        }
        // barrier #2: rendezvous -> ALL waves' chunk-ch loads are in LDS
        BAR();

        const __bf16* Kb = Ks + (ch & 1) * 8192;
        const __bf16* Vb = Vs + (ch & 1) * 8192;

        // ---- S^T = K·Q^T ----
        f32x4 st[2][4] = {};
        __builtin_amdgcn_s_setprio(1);
#pragma unroll
        for (int t = 0; t < 4; ++t)
#pragma unroll
            for (int dt = 0; dt < 4; ++dt) {
                bf16x8 kfv = *(const bf16x8*)(Kb + (t * 4 + dt) * 512 + lane * 8);
                st[0][t] = MFMA16(kfv, qf[0][dt], st[0][t]);
                st[1][t] = MFMA16(kfv, qf[1][dt], st[1][t]);
            }
        __builtin_amdgcn_s_setprio(0);

        bool diag = (ch == nch - 1);
        float alpha[2];
#pragma unroll
        for (int nt = 0; nt < 2; ++nt) {
            if (diag) {
                int qg = q0 + nt * 16 + l16;
#pragma unroll
                for (int t = 0; t < 4; ++t)
#pragma unroll
                    for (int r = 0; r < 4; ++r)
                        if (ch * 64 + t * 16 + quad * 4 + r > qg) st[nt][t][r] = -1e30f;
            }
            float cmax = -1e30f;
#pragma unroll
            for (int t = 0; t < 4; ++t)
                cmax = fmaxf(cmax, fmaxf(fmaxf(st[nt][t][0], st[nt][t][1]),
                                         fmaxf(st[nt][t][2], st[nt][t][3])));
            cmax = fmaxf(cmax, __shfl_xor(cmax, 16));
            cmax = fmaxf(cmax, __shfl_xor(cmax, 32));
            float mnew = fmaxf(m_r[nt], cmax);
            alpha[nt] = __expf(m_r[nt] - mnew);
            m_r[nt] = mnew;
            float ps = 0.f;
#pragma unroll
            for (int t = 0; t < 4; ++t) {
                float p0 = __expf(st[nt][t][0] - mnew);
                float p1 = __expf(st[nt][t][1] - mnew);
                float p2 = __expf(st[nt][t][2] - mnew);
                float p3 = __expf(st[nt][t][3] - mnew);
                ps += (p0 + p1) + (p2 + p3);
                int off = (nt * 2 + (t >> 1)) * 512 + ((t & 1) * 2 + (quad >> 1)) * 128
                          + l16 * 8 + (quad & 1) * 4;
                unsigned long long pk =
                    (unsigned long long)pack_bf16(p0, p1) |
                    ((unsigned long long)pack_bf16(p2, p3) << 32);
                *(unsigned long long*)(Pw + off) = pk;
            }
            ps += __shfl_xor(ps, 16);
            ps += __shfl_xor(ps, 32);
            l_r[nt] = l_r[nt] * alpha[nt] + ps;
        }

        // ---- rescale O ----
#pragma unroll
        for (int mt = 0; mt < 2; ++mt)
#pragma unroll
            for (int r = 0; r < 4; ++r) {
                float alr = __shfl(alpha[mt], quad * 4 + r);
#pragma unroll
                for (int nto = 0; nto < 8; ++nto)
                    o_acc[mt][nto][r] *= alr;
            }

        // ---- O += P·V (P wave-private: no barrier; lgkmcnt orders WAR/RAW) ----
        __builtin_amdgcn_s_setprio(1);
#pragma unroll
        for (int mt = 0; mt < 2; ++mt)
#pragma unroll
            for (int kk = 0; kk < 2; ++kk) {
                bf16x8 pf = *(const bf16x8*)(Pw + (mt * 2 + kk) * 512 + lane * 8);
#pragma unroll
                for (int nto = 0; nto < 8; ++nto) {
                    bf16x8 vf = *(const bf16x8*)(Vb + (nto * 2 + kk) * 512 + lane * 8);
                    o_acc[mt][nto] = MFMA16(pf, vf, o_acc[mt][nto]);
                }
            }
        __builtin_amdgcn_s_setprio(0);
    }

    float* obase = O + (size_t)b * T * CM + (size_t)h * HD;
#pragma unroll
    for (int mt = 0; mt < 2; ++mt) {
        float invl = 1.f / l_r[mt];
#pragma unroll
        for (int r = 0; r < 4; ++r) {
            float ir = __shfl(invl, quad * 4 + r);
            float* orow = obase + (size_t)(q0 + 16 * mt + quad * 4 + r) * CM;
#pragma unroll
            for (int nto = 0; nto < 8; ++nto)
                orow[nto * 16 + l16] = o_acc[mt][nto][r] * ir;
        }
    }
}

extern "C" void kernel_launch(void* const* d_in, const int* in_sizes, int n_in,
                              void* d_out, int out_size, void* d_ws, size_t ws_size,
                              hipStream_t stream) {
    const float* x  = (const float*)d_in[0];
    const float* Wq = (const float*)d_in[1];
    const float* Wk = (const float*)d_in[2];
    const float* Wv = (const float*)d_in[3];
    float* out = (float*)d_out;

    const float qscale = 0.08838834764831845f;  // 128^-0.5

    __bf16* xb = (__bf16*)d_ws;              // 8M elems
    __bf16* Wb = xb + 8388608;               // 6M  [3072][2048] = Wq|Wk|Wv
    __bf16* Qb = Wb + 6291456;               // 8M  [4096][2048]
    __bf16* Kfr = Qb + 8388608;              // 2M  frag-order K
    __bf16* Vfr = Kfr + 2097152;             // 2M  frag-order V

    cvt_all<<<7168, 256, 0, stream>>>(x, Wq, Wk, Wv, xb, Wb);
    gemm_qkv<<<192, 512, 0, stream>>>(xb, Wb, Qb, Kfr, Vfr, qscale);
    attn_mfma<<<512, 256, 0, stream>>>(Qb, Kfr, Vfr, out);
}